// Round 1
// baseline (155.576 us; speedup 1.0000x reference)
//
#include <hip/hip_runtime.h>
#include <cstdint>

#define TPB 256

// ---------------------------------------------------------------------------
// Kernel A: gt = R*kp + t, |gt|^2; thr[i] = clamped self-distance d(i,i);
// zero good-counters and accumulators.
// All arithmetic bit-matches the numpy reference (validated absmax=0.0):
// dot via ascending-k FMA chain, sums via (a+b)+c with contraction off,
// 2*dot via pre-scaled operands (exact).
// ---------------------------------------------------------------------------
__global__ void prep_kernel(const float* __restrict__ kp_before,
                            const float* __restrict__ pred,
                            const float* __restrict__ pose,
                            float4* __restrict__ gt4,
                            float* __restrict__ thr,
                            unsigned int* __restrict__ good,
                            float* __restrict__ accum,
                            int M, int N) {
    int tid = blockIdx.x * blockDim.x + threadIdx.x;
    if (tid < 8) accum[tid] = 0.0f;
    int stride = gridDim.x * blockDim.x;
    for (int i = tid; i < M; i += stride) {
        good[i] = 0u;
        int b = i / N;
        const float* P = pose + b * 12;
        float k0 = kp_before[3*i+0];
        float k1 = kp_before[3*i+1];
        float k2 = kp_before[3*i+2];
        float g0 = fmaf(P[2],  k2, fmaf(P[1], k1, P[0]*k0)) + P[3];
        float g1 = fmaf(P[6],  k2, fmaf(P[5], k1, P[4]*k0)) + P[7];
        float g2 = fmaf(P[10], k2, fmaf(P[9], k1, P[8]*k0)) + P[11];
        float sg;
        {
            #pragma clang fp contract(off)
            sg = (g0*g0 + g1*g1) + g2*g2;   // numpy sum order, no FMA
        }
        gt4[i] = make_float4(g0, g1, g2, sg);

        // self-distance threshold, identical op sequence to the scan loop
        float p0 = pred[3*i+0], p1 = pred[3*i+1], p2 = pred[3*i+2];
        float sp;
        {
            #pragma clang fp contract(off)
            sp = (p0*p0 + p1*p1) + p2*p2;
        }
        float t0 = 2.0f*p0, t1 = 2.0f*p1, t2 = 2.0f*p2;
        float dot2 = fmaf(t2, g2, fmaf(t1, g1, t0*g0));
        float v = (sp + sg) - dot2;
        thr[i] = fmaxf(v, 0.0f);
    }
}

// ---------------------------------------------------------------------------
// Kernel B (rewritten): early-exit existence scan, ONE WAVE PER ROW.
// mask[i]=1 iff argmin_j d(i,j)==i (first-occurrence ties), i.e. no j<i with
// clamp(v)<=dii and no j>i with clamp(v)<dii.  Since d(i,i)'s rank among the
// row's M distances is ~uniform, the first hit appears at expected position
// ~M/rank: expected scan length ~ln(M)~10 of 16384.  Per-pair arithmetic is
// the VERBATIM op sequence of the validated full-scan kernel, so the mask is
// bit-identical.  4x64 j's per iteration bounds the worst row (mask=1) at
// 64 memory-latency round trips.  gt4 (256 KB) is L2-resident.
// ---------------------------------------------------------------------------
#define SCAN_U 4   // 4 chunks of 64 j's per ballot -> 256 j's per iteration

__global__ void __launch_bounds__(TPB) scan_kernel(
        const float* __restrict__ pred,
        const float4* __restrict__ gt4,
        const float* __restrict__ thr,
        unsigned int* __restrict__ good,
        int M) {
    int wid  = (blockIdx.x * blockDim.x + threadIdx.x) >> 6;
    int lane = threadIdx.x & 63;
    if (wid >= M) return;
    int i = __builtin_amdgcn_readfirstlane(wid);   // row index, wave-uniform

    float p0 = pred[3*i+0], p1 = pred[3*i+1], p2 = pred[3*i+2];
    float sp;
    {
        #pragma clang fp contract(off)
        sp = (p0*p0 + p1*p1) + p2*p2;
    }
    float tp0 = 2.0f*p0, tp1 = 2.0f*p1, tp2 = 2.0f*p2;
    float dii = thr[i];

    bool bad = false;
    for (int jb = 0; jb < M; jb += 64 * SCAN_U) {
        int j0 = jb + lane;
        // independent loads issued up front (hide L2 latency within the iter)
        float4 g[SCAN_U];
        int    jj[SCAN_U];
        #pragma unroll
        for (int u = 0; u < SCAN_U; u++) {
            int j = j0 + 64 * u;
            if (j > M - 1) j = M - 1;      // dup of a valid j: harmless for OR
            jj[u] = j;
            g[u] = gt4[j];
        }
        bool h = false;
        #pragma unroll
        for (int u = 0; u < SCAN_U; u++) {
            // verbatim op sequence of the validated kernel:
            float v = (sp + g[u].w) -
                      fmaf(tp2, g[u].z, fmaf(tp1, g[u].y, tp0 * g[u].x));
            float c = fmaxf(v, 0.0f);
            int j = jj[u];
            // (j<i && c<=dii) || (j>i && c<dii)  ==  first-occurrence argmin
            h = h || (c < dii && j != i) || (c == dii && j < i);
        }
        if (__any(h)) { bad = true; break; }
    }
    if (lane == 0) good[i] = bad ? 0u : 1u;
}

// ---------------------------------------------------------------------------
// Kernel C: per-point BCE (balanced groups) + weighted L1; wave reduce then
// atomicAdd into accum[6].
// ---------------------------------------------------------------------------
__device__ inline float wave_red(float v) {
    #pragma unroll
    for (int off = 32; off > 0; off >>= 1) v += __shfl_down(v, off, 64);
    return v;
}

__global__ void finalize_kernel(const float* __restrict__ pred,
                                const float4* __restrict__ gt4,
                                const float* __restrict__ ow,
                                const float* __restrict__ logits,
                                const unsigned int* __restrict__ good,
                                float* __restrict__ accum, int M, int numJ) {
    float werr = 0.f, wsum = 0.f, b1 = 0.f, c1 = 0.f, b0 = 0.f, c0 = 0.f;
    int stride = gridDim.x * blockDim.x;
    for (int i = blockIdx.x * blockDim.x + threadIdx.x; i < M; i += stride) {
        float x = logits[i];
        float l1p = log1pf(expf(-fabsf(x)));   // softplus tail
        if (good[i] == (unsigned int)numJ) {   // label 1: bce = softplus(-x)
            b1 += fmaxf(-x, 0.f) + l1p; c1 += 1.f;
        } else {                               // label 0: bce = softplus(x)
            b0 += fmaxf(x, 0.f) + l1p;  c0 += 1.f;
        }
        float4 g = gt4[i];
        float p0 = pred[3*i+0], p1 = pred[3*i+1], p2 = pred[3*i+2];
        float e = (fabsf(p0 - g.x) + fabsf(p1 - g.y)) + fabsf(p2 - g.z);
        float wi = ow[i];
        werr += wi * e;
        wsum += wi;
    }
    werr = wave_red(werr); wsum = wave_red(wsum);
    b1 = wave_red(b1); c1 = wave_red(c1);
    b0 = wave_red(b0); c0 = wave_red(c0);
    if ((threadIdx.x & 63) == 0) {
        atomicAdd(&accum[0], werr);
        atomicAdd(&accum[1], wsum);
        atomicAdd(&accum[2], b1);
        atomicAdd(&accum[3], c1);
        atomicAdd(&accum[4], b0);
        atomicAdd(&accum[5], c0);
    }
}

// ---------------------------------------------------------------------------
// Kernel D: final scalar combine.
// ---------------------------------------------------------------------------
__global__ void scalar_kernel(const float* __restrict__ accum,
                              float* __restrict__ out) {
    float mean_err = accum[0] / fmaxf(accum[1], 1e-6f);
    float g1 = (accum[3] > 0.f) ? (accum[2] / fmaxf(accum[3], 1.f)) : 0.f;
    float g0 = (accum[5] > 0.f) ? (accum[4] / fmaxf(accum[5], 1.f)) : 0.f;
    out[0] = mean_err + (g0 * 0.5f + g1 * 0.5f);
}

extern "C" void kernel_launch(void* const* d_in, const int* in_sizes, int n_in,
                              void* d_out, int out_size, void* d_ws, size_t ws_size,
                              hipStream_t stream) {
    const float* kp_before = (const float*)d_in[0];
    const float* pred      = (const float*)d_in[1];
    const float* pose      = (const float*)d_in[2];
    const float* ow        = (const float*)d_in[3];
    const float* logits    = (const float*)d_in[4];
    float* out = (float*)d_out;

    int M = in_sizes[3];            // B*N = 16384
    int B = in_sizes[2] / 12;       // 2
    int N = M / B;                  // 8192

    char* ws = (char*)d_ws;
    float4* gt4 = (float4*)ws;                                  // M*16 B
    float* thr = (float*)(ws + (size_t)M * 16);                 // M*4 B
    unsigned int* good = (unsigned int*)(ws + (size_t)M * 20);  // M*4 B
    float* accum = (float*)(ws + (size_t)M * 24);               // 32 B

    int prep_blocks = (M + TPB - 1) / TPB;                      // 64
    hipLaunchKernelGGL(prep_kernel, dim3(prep_blocks), dim3(TPB), 0, stream,
                       kp_before, pred, pose, gt4, thr, good, accum, M, N);

    // one wave per row: M waves = M*64 threads
    int scan_blocks = (M * 64 + TPB - 1) / TPB;                 // 4096
    hipLaunchKernelGGL(scan_kernel, dim3(scan_blocks), dim3(TPB), 0, stream,
                       pred, gt4, thr, good, M);

    hipLaunchKernelGGL(finalize_kernel, dim3(64), dim3(TPB), 0, stream,
                       pred, gt4, ow, logits, good, accum, M, /*numJ=*/1);

    hipLaunchKernelGGL(scalar_kernel, dim3(1), dim3(1), 0, stream,
                       accum, out);
}

// Round 3
// 115.450 us; speedup vs baseline: 1.3476x; 1.3476x over previous
//
#include <hip/hip_runtime.h>
#include <cstdint>

#define TPB 256
#define K_PRE 256      // prefix columns decided in the fused kernel (== TPB)
#define NSLICE 16      // suffix j-slices per row-range

// ---------------------------------------------------------------------------
// Kernel 1 (fused prep + prefix-decide).
// Per thread (one row i):
//   gt = R*kp + t, |gt|^2  -> gt4[i];  thr[i] = clamped self-distance d(i,i).
// Per block: redundantly recompute gt4[0..K_PRE) into LDS (9 FMA/row, cheap),
// then decide each row against the K_PRE-column prefix:
//   bad iff exists j<i with clamp(v)<=dii or j>i with clamp(v)<dii.
// Rows surviving the prefix (expected ~M/K_PRE ~ 64) are candidates
// (good[i]=1) and get the remaining columns checked by suffix_kernel.
// All arithmetic bit-matches the validated baseline (absmax=0.0): dot via
// ascending-k FMA chain, sums via (a+b)+c with contraction off, 2*dot via
// pre-scaled operands (exact), clamp commutes with min.
// ---------------------------------------------------------------------------
__global__ void __launch_bounds__(TPB) fused_prep_prefix(
        const float* __restrict__ kp_before,
        const float* __restrict__ pred,
        const float* __restrict__ pose,
        float4* __restrict__ gt4,
        float* __restrict__ thr,
        unsigned int* __restrict__ good,
        float* __restrict__ accum,
        int M, int N) {
    __shared__ float4 shg[K_PRE];
    int tid = threadIdx.x;
    int i = blockIdx.x * TPB + tid;

    if (blockIdx.x == 0 && tid < 8) accum[tid] = 0.0f;  // incl. ctr @ [7]

    float sp = 0.f, tp0 = 0.f, tp1 = 0.f, tp2 = 0.f, dii = 0.f;
    if (i < M) {
        int b = i / N;
        const float* P = pose + b * 12;
        float k0 = kp_before[3*i+0];
        float k1 = kp_before[3*i+1];
        float k2 = kp_before[3*i+2];
        float g0 = fmaf(P[2],  k2, fmaf(P[1], k1, P[0]*k0)) + P[3];
        float g1 = fmaf(P[6],  k2, fmaf(P[5], k1, P[4]*k0)) + P[7];
        float g2 = fmaf(P[10], k2, fmaf(P[9], k1, P[8]*k0)) + P[11];
        float sg;
        {
            #pragma clang fp contract(off)
            sg = (g0*g0 + g1*g1) + g2*g2;   // numpy sum order, no FMA
        }
        gt4[i] = make_float4(g0, g1, g2, sg);

        float p0 = pred[3*i+0], p1 = pred[3*i+1], p2 = pred[3*i+2];
        {
            #pragma clang fp contract(off)
            sp = (p0*p0 + p1*p1) + p2*p2;
        }
        tp0 = 2.0f*p0; tp1 = 2.0f*p1; tp2 = 2.0f*p2;
        float dot2 = fmaf(tp2, g2, fmaf(tp1, g1, tp0*g0));
        float v = (sp + sg) - dot2;
        dii = fmaxf(v, 0.0f);
        thr[i] = dii;
    }

    // redundant per-block recompute of prefix gt4 rows into LDS
    // (bitwise identical expression/inputs -> identical bits to gt4[0..K_PRE))
    if (tid < K_PRE && tid < M) {
        int jp = tid;
        const float* Pj = pose + (jp / N) * 12;
        float q0 = kp_before[3*jp+0];
        float q1 = kp_before[3*jp+1];
        float q2 = kp_before[3*jp+2];
        float h0 = fmaf(Pj[2],  q2, fmaf(Pj[1], q1, Pj[0]*q0)) + Pj[3];
        float h1 = fmaf(Pj[6],  q2, fmaf(Pj[5], q1, Pj[4]*q0)) + Pj[7];
        float h2 = fmaf(Pj[10], q2, fmaf(Pj[9], q1, Pj[8]*q0)) + Pj[11];
        float hh;
        {
            #pragma clang fp contract(off)
            hh = (h0*h0 + h1*h1) + h2*h2;
        }
        shg[jp] = make_float4(h0, h1, h2, hh);
    }
    __syncthreads();

    if (i >= M) return;

    bool bad;
    if (i >= K_PRE) {
        // whole prefix is j < i: bad iff clamp(min v) <= dii
        float mn = __uint_as_float(0x7f7fffffu);  // FLT_MAX
        for (int j = 0; j < K_PRE; j++) {
            float4 g = shg[j];
            float v = (sp + g.w) -
                      fmaf(tp2, g.z, fmaf(tp1, g.y, tp0 * g.x));
            mn = fminf(mn, v);
        }
        bad = (fmaxf(mn, 0.0f) <= dii);
    } else {
        // split at i: j<i uses <=, j>i uses <, j==i skipped
        float mnl = __uint_as_float(0x7f7fffffu);
        float mnr = __uint_as_float(0x7f7fffffu);
        for (int j = 0; j < i; j++) {
            float4 g = shg[j];
            float v = (sp + g.w) -
                      fmaf(tp2, g.z, fmaf(tp1, g.y, tp0 * g.x));
            mnl = fminf(mnl, v);
        }
        for (int j = i + 1; j < K_PRE; j++) {
            float4 g = shg[j];
            float v = (sp + g.w) -
                      fmaf(tp2, g.z, fmaf(tp1, g.y, tp0 * g.x));
            mnr = fminf(mnr, v);
        }
        bad = (fmaxf(mnl, 0.0f) <= dii) || (fmaxf(mnr, 0.0f) < dii);
    }
    good[i] = bad ? 0u : 1u;
}

// ---------------------------------------------------------------------------
// Kernel 2 (suffix): only candidate rows (good==1, expected ~64 of 16384)
// get columns [K_PRE, M) checked.  Grid = (M/TPB row-ranges) x NSLICE
// j-slices; each block gathers its range's candidates into shared memory
// (expected ~1) and scans its ~1008-column slice with 256 threads (<=4 j's
// per thread).  Throughput-parallel: no serialized latency chain.
// Benign race: blocks only ever write 0 to good[].
// ---------------------------------------------------------------------------
__global__ void __launch_bounds__(TPB) suffix_kernel(
        const float* __restrict__ pred,
        const float4* __restrict__ gt4,
        const float* __restrict__ thr,
        unsigned int* __restrict__ good,
        int M) {
    __shared__ int cands[TPB];
    __shared__ int ncand;
    int s  = blockIdx.x & (NSLICE - 1);
    int r0 = (blockIdx.x / NSLICE) * TPB;
    if (threadIdx.x == 0) ncand = 0;
    __syncthreads();
    int i = r0 + threadIdx.x;
    if (i < M && good[i] == 1u) {
        int p = atomicAdd(&ncand, 1);
        cands[p] = i;
    }
    __syncthreads();
    int nc = ncand;
    if (nc == 0) return;

    int total = M - K_PRE;
    int per = (total + NSLICE - 1) / NSLICE;
    int js = K_PRE + s * per;
    int je = js + per; if (je > M) je = M;

    for (int e = 0; e < nc; e++) {
        int r = cands[e];
        float p0 = pred[3*r+0], p1 = pred[3*r+1], p2 = pred[3*r+2];
        float sp;
        {
            #pragma clang fp contract(off)
            sp = (p0*p0 + p1*p1) + p2*p2;
        }
        float tp0 = 2.0f*p0, tp1 = 2.0f*p1, tp2 = 2.0f*p2;
        float dii = thr[r];
        bool h = false;
        for (int j = js + threadIdx.x; j < je; j += TPB) {
            float4 g = gt4[j];
            float v = (sp + g.w) -
                      fmaf(tp2, g.z, fmaf(tp1, g.y, tp0 * g.x));
            float c = fmaxf(v, 0.0f);
            h = h || (c < dii && j != r) || (c == dii && j < r);
        }
        if (h) good[r] = 0u;
    }
}

// ---------------------------------------------------------------------------
// Kernel 3: per-point BCE (balanced groups) + weighted L1; wave reduce,
// atomicAdd into accum[0..5]; last-block-done pattern computes the final
// scalar (saves the separate scalar launch).  ctr lives in accum[7].
// ---------------------------------------------------------------------------
__device__ inline float wave_red(float v) {
    #pragma unroll
    for (int off = 32; off > 0; off >>= 1) v += __shfl_down(v, off, 64);
    return v;
}

__global__ void __launch_bounds__(TPB) finalize_kernel(
        const float* __restrict__ pred,
        const float4* __restrict__ gt4,
        const float* __restrict__ ow,
        const float* __restrict__ logits,
        const unsigned int* __restrict__ good,
        float* __restrict__ accum,
        float* __restrict__ out,
        int M) {
    float werr = 0.f, wsum = 0.f, b1 = 0.f, c1 = 0.f, b0 = 0.f, c0 = 0.f;
    int stride = gridDim.x * blockDim.x;
    for (int i = blockIdx.x * blockDim.x + threadIdx.x; i < M; i += stride) {
        float x = logits[i];
        float l1p = log1pf(expf(-fabsf(x)));   // softplus tail
        if (good[i] == 1u) {                   // label 1: bce = softplus(-x)
            b1 += fmaxf(-x, 0.f) + l1p; c1 += 1.f;
        } else {                               // label 0: bce = softplus(x)
            b0 += fmaxf(x, 0.f) + l1p;  c0 += 1.f;
        }
        float4 g = gt4[i];
        float p0 = pred[3*i+0], p1 = pred[3*i+1], p2 = pred[3*i+2];
        float e = (fabsf(p0 - g.x) + fabsf(p1 - g.y)) + fabsf(p2 - g.z);
        float wi = ow[i];
        werr += wi * e;
        wsum += wi;
    }
    werr = wave_red(werr); wsum = wave_red(wsum);
    b1 = wave_red(b1); c1 = wave_red(c1);
    b0 = wave_red(b0); c0 = wave_red(c0);
    if ((threadIdx.x & 63) == 0) {
        atomicAdd(&accum[0], werr);
        atomicAdd(&accum[1], wsum);
        atomicAdd(&accum[2], b1);
        atomicAdd(&accum[3], c1);
        atomicAdd(&accum[4], b0);
        atomicAdd(&accum[5], c0);
    }
    __threadfence();          // make this block's atomics device-visible
    __syncthreads();
    if (threadIdx.x == 0) {
        unsigned int* ctr = (unsigned int*)&accum[7];
        unsigned int old = atomicAdd(ctr, 1u);
        if (old == gridDim.x - 1) {
            // atomic reads: guaranteed-coherent path for others' atomics
            float a0 = atomicAdd(&accum[0], 0.f);
            float a1 = atomicAdd(&accum[1], 0.f);
            float a2 = atomicAdd(&accum[2], 0.f);
            float a3 = atomicAdd(&accum[3], 0.f);
            float a4 = atomicAdd(&accum[4], 0.f);
            float a5 = atomicAdd(&accum[5], 0.f);
            float mean_err = a0 / fmaxf(a1, 1e-6f);
            float g1v = (a3 > 0.f) ? (a2 / fmaxf(a3, 1.f)) : 0.f;
            float g0v = (a5 > 0.f) ? (a4 / fmaxf(a5, 1.f)) : 0.f;
            out[0] = mean_err + (g0v * 0.5f + g1v * 0.5f);
        }
    }
}

extern "C" void kernel_launch(void* const* d_in, const int* in_sizes, int n_in,
                              void* d_out, int out_size, void* d_ws, size_t ws_size,
                              hipStream_t stream) {
    const float* kp_before = (const float*)d_in[0];
    const float* pred      = (const float*)d_in[1];
    const float* pose      = (const float*)d_in[2];
    const float* ow        = (const float*)d_in[3];
    const float* logits    = (const float*)d_in[4];
    float* out = (float*)d_out;

    int M = in_sizes[3];            // B*N = 16384
    int B = in_sizes[2] / 12;       // 2
    int N = M / B;                  // 8192

    char* ws = (char*)d_ws;
    float4* gt4 = (float4*)ws;                                  // M*16 B
    float* thr = (float*)(ws + (size_t)M * 16);                 // M*4 B
    unsigned int* good = (unsigned int*)(ws + (size_t)M * 20);  // M*4 B
    float* accum = (float*)(ws + (size_t)M * 24);               // 32 B ([7]=ctr)

    int nrb = (M + TPB - 1) / TPB;                              // 64 row-blocks

    hipLaunchKernelGGL(fused_prep_prefix, dim3(nrb), dim3(TPB), 0, stream,
                       kp_before, pred, pose, gt4, thr, good, accum, M, N);

    hipLaunchKernelGGL(suffix_kernel, dim3(nrb * NSLICE), dim3(TPB), 0, stream,
                       pred, gt4, thr, good, M);

    hipLaunchKernelGGL(finalize_kernel, dim3(64), dim3(TPB), 0, stream,
                       pred, gt4, ow, logits, good, accum, out, M);
}